// Round 2
// baseline (164.868 us; speedup 1.0000x reference)
//
#include <hip/hip_runtime.h>

// WaveletLoss: 3-level Haar DWT + soft-threshold + weighted mean-abs-diff.
// B=64, C=1, H=W=512.
// R1: one thread per 4x4 pixel block (levels 1-2 in registers); level 3 is
// closed via __shfl_xor across the 4 consecutive lanes holding the 2x2 cA2
// neighborhood. 1,048,576 threads = 16,384 waves = 64 waves/CU.

#define IMG_H 512
#define IMG_W 512
#define N_BATCH 64

#define THR1 (50.0f / 255.0f)
#define THR2 (25.0f / 255.0f)
#define THR3 (12.5f / 255.0f)

__device__ __forceinline__ float softthr(float x, float thr) {
    float m = fmaxf(fabsf(x) - thr, 0.0f);
    return copysignf(m, x);
}

__device__ __forceinline__ float detail_term(float p, float t, float thr) {
    return fabsf(softthr(p, thr) - softthr(t, thr));
}

__device__ __forceinline__ void haar_quad(float a, float b, float c, float d,
                                          float& cA, float& cH, float& cV, float& cD) {
    cA = 0.5f * (a + b + c + d);
    cH = 0.5f * (a + b - c - d);
    cV = 0.5f * (a - b + c - d);
    cD = 0.5f * (a - b - c + d);
}

__global__ void zero_out_kernel(float* out) { out[0] = 0.0f; }

__global__ __launch_bounds__(256)
void wavelet_loss_kernel(const float* __restrict__ pred,
                         const float* __restrict__ target,
                         float* __restrict__ out) {
    const int tid  = blockIdx.x * 256 + threadIdx.x;   // 0..1048575
    const int img  = tid >> 14;                        // 16384 threads / image
    const int rem  = tid & 16383;
    const int w    = rem >> 6;                         // wave within image 0..255
    const int lane = rem & 63;
    const int wy   = w >> 2;                           // 0..63
    const int wx   = w & 3;                            // 0..3
    const int q    = lane >> 2;                        // 0..15
    const int sub  = lane & 3;                         // 2x2 position in cA2 group
    const int dy   = sub >> 1;
    const int dx   = sub & 1;

    const int r2 = wy * 2 + dy;                        // cA2 row   0..127
    const int c2 = wx * 32 + q * 2 + dx;               // cA2 col   0..127

    const long base = (long)img * (IMG_H * IMG_W) + (long)(r2 * 4) * IMG_W + c2 * 4;

    // 8 float4 loads, all independent -> all in flight at once.
    float4 p0 = *(const float4*)(pred + base);
    float4 p1 = *(const float4*)(pred + base + IMG_W);
    float4 p2 = *(const float4*)(pred + base + 2 * IMG_W);
    float4 p3 = *(const float4*)(pred + base + 3 * IMG_W);
    float4 t0 = *(const float4*)(target + base);
    float4 t1 = *(const float4*)(target + base + IMG_W);
    float4 t2 = *(const float4*)(target + base + 2 * IMG_W);
    float4 t3 = *(const float4*)(target + base + 3 * IMG_W);

    float s1 = 0.0f;
    float cA1p[4], cA1t[4];

    // ---- level 1: 4 quads of the 4x4 block ----
    {
        float cA, cH, cV, cD, cAt_, cHt, cVt, cDt;
        // quad (0,0)
        haar_quad(p0.x, p0.y, p1.x, p1.y, cA, cH, cV, cD);
        haar_quad(t0.x, t0.y, t1.x, t1.y, cAt_, cHt, cVt, cDt);
        s1 += detail_term(cH, cHt, THR1) + detail_term(cV, cVt, THR1) + detail_term(cD, cDt, THR1);
        cA1p[0] = cA; cA1t[0] = cAt_;
        // quad (0,1)
        haar_quad(p0.z, p0.w, p1.z, p1.w, cA, cH, cV, cD);
        haar_quad(t0.z, t0.w, t1.z, t1.w, cAt_, cHt, cVt, cDt);
        s1 += detail_term(cH, cHt, THR1) + detail_term(cV, cVt, THR1) + detail_term(cD, cDt, THR1);
        cA1p[1] = cA; cA1t[1] = cAt_;
        // quad (1,0)
        haar_quad(p2.x, p2.y, p3.x, p3.y, cA, cH, cV, cD);
        haar_quad(t2.x, t2.y, t3.x, t3.y, cAt_, cHt, cVt, cDt);
        s1 += detail_term(cH, cHt, THR1) + detail_term(cV, cVt, THR1) + detail_term(cD, cDt, THR1);
        cA1p[2] = cA; cA1t[2] = cAt_;
        // quad (1,1)
        haar_quad(p2.z, p2.w, p3.z, p3.w, cA, cH, cV, cD);
        haar_quad(t2.z, t2.w, t3.z, t3.w, cAt_, cHt, cVt, cDt);
        s1 += detail_term(cH, cHt, THR1) + detail_term(cV, cVt, THR1) + detail_term(cD, cDt, THR1);
        cA1p[3] = cA; cA1t[3] = cAt_;
    }

    // ---- level 2: one quad per thread ----
    float s2 = 0.0f;
    float cA2p, cA2t;
    {
        float cH, cV, cD, cHt, cVt, cDt;
        haar_quad(cA1p[0], cA1p[1], cA1p[2], cA1p[3], cA2p, cH, cV, cD);
        haar_quad(cA1t[0], cA1t[1], cA1t[2], cA1t[3], cA2t, cHt, cVt, cDt);
        s2 += detail_term(cH, cHt, THR2) + detail_term(cV, cVt, THR2) + detail_term(cD, cDt, THR2);
    }

    // ---- level 3: gather 2x2 cA2 neighborhood across lanes sub=0..3 ----
    float s3 = 0.0f;
    {
        float vp[4], vt[4];
        vp[sub]     = cA2p;               vt[sub]     = cA2t;
        vp[sub ^ 1] = __shfl_xor(cA2p, 1); vt[sub ^ 1] = __shfl_xor(cA2t, 1);
        vp[sub ^ 2] = __shfl_xor(cA2p, 2); vt[sub ^ 2] = __shfl_xor(cA2t, 2);
        vp[sub ^ 3] = __shfl_xor(cA2p, 3); vt[sub ^ 3] = __shfl_xor(cA2t, 3);
        float cA, cH, cV, cD, cAt_, cHt, cVt, cDt;
        haar_quad(vp[0], vp[1], vp[2], vp[3], cA, cH, cV, cD);
        haar_quad(vt[0], vt[1], vt[2], vt[3], cAt_, cHt, cVt, cDt);
        s3 = detail_term(cH, cHt, THR3) + detail_term(cV, cVt, THR3) + detail_term(cD, cDt, THR3);
    }

    // weights: 1/(level * 3 * N_level)
    constexpr float W1 = 1.0f / (1.0f * 3.0f * (float)(N_BATCH * 256 * 256));
    constexpr float W2 = 1.0f / (2.0f * 3.0f * (float)(N_BATCH * 128 * 128));
    constexpr float W3 = 1.0f / (3.0f * 3.0f * (float)(N_BATCH * 64 * 64));

    float v = W1 * s1 + W2 * s2;
    v += (sub == 0 ? W3 : 0.0f) * s3;   // level-3 counted once per 2x2 group

    // wave (64-lane) reduction
    #pragma unroll
    for (int off = 32; off > 0; off >>= 1)
        v += __shfl_down(v, off, 64);

    __shared__ float wave_sums[4];
    const int lane_b = threadIdx.x & 63;
    const int wave_b = threadIdx.x >> 6;
    if (lane_b == 0) wave_sums[wave_b] = v;
    __syncthreads();
    if (threadIdx.x == 0) {
        float s = wave_sums[0] + wave_sums[1] + wave_sums[2] + wave_sums[3];
        atomicAdd(out, s);
    }
}

extern "C" void kernel_launch(void* const* d_in, const int* in_sizes, int n_in,
                              void* d_out, int out_size, void* d_ws, size_t ws_size,
                              hipStream_t stream) {
    const float* pred   = (const float*)d_in[0];
    const float* target = (const float*)d_in[1];
    float* out = (float*)d_out;

    zero_out_kernel<<<1, 1, 0, stream>>>(out);

    // 64 images * 128*128 threads (one per 4x4 block) = 1,048,576 threads
    wavelet_loss_kernel<<<4096, 256, 0, stream>>>(pred, target, out);
}

// Round 3
// 147.798 us; speedup vs baseline: 1.1155x; 1.1155x over previous
//
#include <hip/hip_runtime.h>

// WaveletLoss: 3-level Haar DWT + soft-threshold + weighted mean-abs-diff.
// B=64, C=1, H=W=512.
// R2: one thread per 8x8 block (pyramid fully in registers, zero cross-lane),
// ALL 32 float4 loads hoisted before compute (max memory-level parallelism),
// no atomics: per-block partials -> d_ws, one-block reducer writes out[0].

#define IMG_H 512
#define IMG_W 512
#define N_BATCH 64

#define THR1 (50.0f / 255.0f)
#define THR2 (25.0f / 255.0f)
#define THR3 (12.5f / 255.0f)

#define NBLOCKS 1024

__device__ __forceinline__ float softthr(float x, float thr) {
    float m = fmaxf(fabsf(x) - thr, 0.0f);
    return copysignf(m, x);
}

__device__ __forceinline__ float detail_term(float p, float t, float thr) {
    return fabsf(softthr(p, thr) - softthr(t, thr));
}

__device__ __forceinline__ void haar_quad(float a, float b, float c, float d,
                                          float& cA, float& cH, float& cV, float& cD) {
    cA = 0.5f * (a + b + c + d);
    cH = 0.5f * (a + b - c - d);
    cV = 0.5f * (a - b + c - d);
    cD = 0.5f * (a - b - c + d);
}

__global__ __launch_bounds__(256, 2)
void wavelet_main(const float* __restrict__ pred,
                  const float* __restrict__ target,
                  float* __restrict__ ws) {
    const int tid = blockIdx.x * 256 + threadIdx.x;
    const int b   = tid >> 12;        // image
    const int rem = tid & 4095;
    const int by  = rem >> 6;
    const int bx  = rem & 63;

    const long base = (long)b * (IMG_H * IMG_W) + (long)(by * 8) * IMG_W + bx * 8;

    // ---- hoist ALL loads: 16 float4 per input, rows 0..7, halves 0..1 ----
    float4 p[16], t[16];
    #pragma unroll
    for (int r = 0; r < 8; ++r) {
        p[r * 2]     = *(const float4*)(pred + base + r * IMG_W);
        p[r * 2 + 1] = *(const float4*)(pred + base + r * IMG_W + 4);
    }
    #pragma unroll
    for (int r = 0; r < 8; ++r) {
        t[r * 2]     = *(const float4*)(target + base + r * IMG_W);
        t[r * 2 + 1] = *(const float4*)(target + base + r * IMG_W + 4);
    }

    float s1 = 0.0f, s2 = 0.0f, s3 = 0.0f;
    float cA1p[16], cA1t[16];

    // ---- level 1: quads (i,j), i,j in 0..3 ----
    #pragma unroll
    for (int i = 0; i < 4; ++i) {
        #pragma unroll
        for (int j = 0; j < 4; ++j) {
            const int h = j >> 1;           // which float4 half
            const bool odd = (j & 1);       // cols (x,y) vs (z,w)
            const float4 pu = p[(2 * i) * 2 + h];
            const float4 pl = p[(2 * i + 1) * 2 + h];
            const float4 tu = t[(2 * i) * 2 + h];
            const float4 tl = t[(2 * i + 1) * 2 + h];
            const float pa = odd ? pu.z : pu.x, pb = odd ? pu.w : pu.y;
            const float pc = odd ? pl.z : pl.x, pd = odd ? pl.w : pl.y;
            const float ta = odd ? tu.z : tu.x, tb = odd ? tu.w : tu.y;
            const float tc = odd ? tl.z : tl.x, td = odd ? tl.w : tl.y;

            float cA, cH, cV, cD, cAt, cHt, cVt, cDt;
            haar_quad(pa, pb, pc, pd, cA, cH, cV, cD);
            haar_quad(ta, tb, tc, td, cAt, cHt, cVt, cDt);
            s1 += detail_term(cH, cHt, THR1)
                + detail_term(cV, cVt, THR1)
                + detail_term(cD, cDt, THR1);
            cA1p[i * 4 + j] = cA;
            cA1t[i * 4 + j] = cAt;
        }
    }

    // ---- level 2: 4x4 cA1 -> 2x2 ----
    float cA2p[4], cA2t[4];
    #pragma unroll
    for (int i2 = 0; i2 < 2; ++i2) {
        #pragma unroll
        for (int j2 = 0; j2 < 2; ++j2) {
            int i = 2 * i2, j = 2 * j2;
            float cA, cH, cV, cD, cAt, cHt, cVt, cDt;
            haar_quad(cA1p[i * 4 + j], cA1p[i * 4 + j + 1],
                      cA1p[(i + 1) * 4 + j], cA1p[(i + 1) * 4 + j + 1],
                      cA, cH, cV, cD);
            haar_quad(cA1t[i * 4 + j], cA1t[i * 4 + j + 1],
                      cA1t[(i + 1) * 4 + j], cA1t[(i + 1) * 4 + j + 1],
                      cAt, cHt, cVt, cDt);
            s2 += detail_term(cH, cHt, THR2)
                + detail_term(cV, cVt, THR2)
                + detail_term(cD, cDt, THR2);
            cA2p[i2 * 2 + j2] = cA;
            cA2t[i2 * 2 + j2] = cAt;
        }
    }

    // ---- level 3 ----
    {
        float cA, cH, cV, cD, cAt, cHt, cVt, cDt;
        haar_quad(cA2p[0], cA2p[1], cA2p[2], cA2p[3], cA, cH, cV, cD);
        haar_quad(cA2t[0], cA2t[1], cA2t[2], cA2t[3], cAt, cHt, cVt, cDt);
        s3 += detail_term(cH, cHt, THR3)
            + detail_term(cV, cVt, THR3)
            + detail_term(cD, cDt, THR3);
    }

    constexpr float W1 = 1.0f / (1.0f * 3.0f * (float)(N_BATCH * 256 * 256));
    constexpr float W2 = 1.0f / (2.0f * 3.0f * (float)(N_BATCH * 128 * 128));
    constexpr float W3 = 1.0f / (3.0f * 3.0f * (float)(N_BATCH * 64 * 64));

    float v = W1 * s1 + W2 * s2 + W3 * s3;

    // wave reduction (64 lanes)
    #pragma unroll
    for (int off = 32; off > 0; off >>= 1)
        v += __shfl_down(v, off, 64);

    __shared__ float wave_sums[4];
    const int lane = threadIdx.x & 63;
    const int wave = threadIdx.x >> 6;
    if (lane == 0) wave_sums[wave] = v;
    __syncthreads();
    if (threadIdx.x == 0) {
        ws[blockIdx.x] = wave_sums[0] + wave_sums[1] + wave_sums[2] + wave_sums[3];
    }
}

__global__ __launch_bounds__(256)
void wavelet_reduce(const float* __restrict__ ws, float* __restrict__ out) {
    const int tidx = threadIdx.x;
    float v = ws[tidx] + ws[tidx + 256] + ws[tidx + 512] + ws[tidx + 768];

    #pragma unroll
    for (int off = 32; off > 0; off >>= 1)
        v += __shfl_down(v, off, 64);

    __shared__ float wave_sums[4];
    const int lane = tidx & 63;
    const int wave = tidx >> 6;
    if (lane == 0) wave_sums[wave] = v;
    __syncthreads();
    if (tidx == 0)
        out[0] = wave_sums[0] + wave_sums[1] + wave_sums[2] + wave_sums[3];
}

extern "C" void kernel_launch(void* const* d_in, const int* in_sizes, int n_in,
                              void* d_out, int out_size, void* d_ws, size_t ws_size,
                              hipStream_t stream) {
    const float* pred   = (const float*)d_in[0];
    const float* target = (const float*)d_in[1];
    float* out = (float*)d_out;
    float* ws  = (float*)d_ws;   // needs NBLOCKS floats = 4 KB

    wavelet_main<<<NBLOCKS, 256, 0, stream>>>(pred, target, ws);
    wavelet_reduce<<<1, 256, 0, stream>>>(ws, out);
}

// Round 4
// 141.356 us; speedup vs baseline: 1.1663x; 1.0456x over previous
//
#include <hip/hip_runtime.h>

// WaveletLoss: 3-level Haar DWT + soft-threshold + weighted mean-abs-diff.
// B=64, C=1, H=W=512.
// R3: occupancy-first. __launch_bounds__(256,8) -> VGPR<=64 -> 8 waves/SIMD,
// 2048 blocks = 32 resident waves/CU (full). One thread per 4x4 block per
// grid-stride iteration; dense coalesced float4 loads (lane li covers
// cols 4*li..4*li+3 -> 512B contiguous per half-wave per instruction).
// Levels 1-2 in registers; level 3 via __shfl_xor(1)/(32). No atomics.

#define IMG_H 512
#define IMG_W 512
#define N_BATCH 64

#define THR1 (50.0f / 255.0f)
#define THR2 (25.0f / 255.0f)
#define THR3 (12.5f / 255.0f)

#define GRID_BLOCKS 2048
#define N_ITERS 2   // 2048*256*2 = 1,048,576 = 64 images * 128*128 blocks

__device__ __forceinline__ float softthr(float x, float thr) {
    float m = fmaxf(fabsf(x) - thr, 0.0f);
    return copysignf(m, x);
}

__device__ __forceinline__ float detail_term(float p, float t, float thr) {
    return fabsf(softthr(p, thr) - softthr(t, thr));
}

__device__ __forceinline__ void haar_quad(float a, float b, float c, float d,
                                          float& cA, float& cH, float& cV, float& cD) {
    cA = 0.5f * (a + b + c + d);
    cH = 0.5f * (a + b - c - d);
    cV = 0.5f * (a - b + c - d);
    cD = 0.5f * (a - b - c + d);
}

__global__ __launch_bounds__(256, 8)
void wavelet_main(const float* __restrict__ pred,
                  const float* __restrict__ target,
                  float* __restrict__ ws) {
    constexpr float W1 = 1.0f / (1.0f * 3.0f * (float)(N_BATCH * 256 * 256));
    constexpr float W2 = 1.0f / (2.0f * 3.0f * (float)(N_BATCH * 128 * 128));
    constexpr float W3 = 1.0f / (3.0f * 3.0f * (float)(N_BATCH * 64 * 64));

    const int tid0 = blockIdx.x * 256 + threadIdx.x;
    float acc = 0.0f;

    #pragma unroll
    for (int iter = 0; iter < N_ITERS; ++iter) {
        const int it   = tid0 + iter * (GRID_BLOCKS * 256);
        const int lane = it & 63;
        const int wv   = it >> 6;          // global wave-work id, 0..16383
        const int img  = wv >> 8;          // 256 waves per image
        const int ww   = wv & 255;
        const int wcy  = ww >> 2;          // 0..63: block-row pair
        const int wcx  = ww & 3;           // 0..3 : 32-block col group
        const int half = lane >> 5;        // 0: even block-row, 1: odd
        const int li   = lane & 31;

        const int r0 = 8 * wcy + 4 * half;       // pixel row of 4x4 block
        const int c0 = 128 * wcx + 4 * li;       // pixel col of 4x4 block
        const long base = (long)img * (IMG_H * IMG_W) + (long)r0 * IMG_W + c0;

        // 8 independent dense loads (one float4 per row, both inputs)
        const float4 p0 = *(const float4*)(pred + base);
        const float4 p1 = *(const float4*)(pred + base + IMG_W);
        const float4 p2 = *(const float4*)(pred + base + 2 * IMG_W);
        const float4 p3 = *(const float4*)(pred + base + 3 * IMG_W);
        const float4 t0 = *(const float4*)(target + base);
        const float4 t1 = *(const float4*)(target + base + IMG_W);
        const float4 t2 = *(const float4*)(target + base + 2 * IMG_W);
        const float4 t3 = *(const float4*)(target + base + 3 * IMG_W);

        // ---- level 1: 4 quads ----
        float s1 = 0.0f;
        float cA1p[4], cA1t[4];
        {
            float cA, cH, cV, cD, cAt, cHt, cVt, cDt;
            haar_quad(p0.x, p0.y, p1.x, p1.y, cA, cH, cV, cD);
            haar_quad(t0.x, t0.y, t1.x, t1.y, cAt, cHt, cVt, cDt);
            s1 += detail_term(cH, cHt, THR1) + detail_term(cV, cVt, THR1) + detail_term(cD, cDt, THR1);
            cA1p[0] = cA; cA1t[0] = cAt;

            haar_quad(p0.z, p0.w, p1.z, p1.w, cA, cH, cV, cD);
            haar_quad(t0.z, t0.w, t1.z, t1.w, cAt, cHt, cVt, cDt);
            s1 += detail_term(cH, cHt, THR1) + detail_term(cV, cVt, THR1) + detail_term(cD, cDt, THR1);
            cA1p[1] = cA; cA1t[1] = cAt;

            haar_quad(p2.x, p2.y, p3.x, p3.y, cA, cH, cV, cD);
            haar_quad(t2.x, t2.y, t3.x, t3.y, cAt, cHt, cVt, cDt);
            s1 += detail_term(cH, cHt, THR1) + detail_term(cV, cVt, THR1) + detail_term(cD, cDt, THR1);
            cA1p[2] = cA; cA1t[2] = cAt;

            haar_quad(p2.z, p2.w, p3.z, p3.w, cA, cH, cV, cD);
            haar_quad(t2.z, t2.w, t3.z, t3.w, cAt, cHt, cVt, cDt);
            s1 += detail_term(cH, cHt, THR1) + detail_term(cV, cVt, THR1) + detail_term(cD, cDt, THR1);
            cA1p[3] = cA; cA1t[3] = cAt;
        }

        // ---- level 2: one quad ----
        float s2 = 0.0f;
        float cA2p, cA2t;
        {
            float cH, cV, cD, cHt, cVt, cDt;
            haar_quad(cA1p[0], cA1p[1], cA1p[2], cA1p[3], cA2p, cH, cV, cD);
            haar_quad(cA1t[0], cA1t[1], cA1t[2], cA1t[3], cA2t, cHt, cVt, cDt);
            s2 = detail_term(cH, cHt, THR2) + detail_term(cV, cVt, THR2) + detail_term(cD, cDt, THR2);
        }

        // ---- level 3: 2x2 cA2 via shuffles (xor1 = horiz, xor32 = vert) ----
        float s3 = 0.0f;
        {
            float pV = __shfl_xor(cA2p, 32);
            float tV = __shfl_xor(cA2t, 32);
            float pH = __shfl_xor(cA2p, 1);
            float tH = __shfl_xor(cA2t, 1);
            float pD = __shfl_xor(pV, 1);
            float tD = __shfl_xor(tV, 1);
            // owner lane (half==0, li even): a=own, b=H, c=V, d=D
            float cA, cH, cV, cD, cAt, cHt, cVt, cDt;
            haar_quad(cA2p, pH, pV, pD, cA, cH, cV, cD);
            haar_quad(cA2t, tH, tV, tD, cAt, cHt, cVt, cDt);
            s3 = detail_term(cH, cHt, THR3) + detail_term(cV, cVt, THR3) + detail_term(cD, cDt, THR3);
        }
        const float w3 = ((lane & 33) == 0) ? W3 : 0.0f;   // half==0 && li even

        acc += W1 * s1 + W2 * s2 + w3 * s3;
    }

    // wave reduction (64 lanes)
    #pragma unroll
    for (int off = 32; off > 0; off >>= 1)
        acc += __shfl_down(acc, off, 64);

    __shared__ float wave_sums[4];
    const int lane_b = threadIdx.x & 63;
    const int wave_b = threadIdx.x >> 6;
    if (lane_b == 0) wave_sums[wave_b] = acc;
    __syncthreads();
    if (threadIdx.x == 0)
        ws[blockIdx.x] = wave_sums[0] + wave_sums[1] + wave_sums[2] + wave_sums[3];
}

__global__ __launch_bounds__(256)
void wavelet_reduce(const float* __restrict__ ws, float* __restrict__ out) {
    const int tidx = threadIdx.x;
    float v = 0.0f;
    #pragma unroll
    for (int k = 0; k < GRID_BLOCKS / 256; ++k)
        v += ws[tidx + k * 256];

    #pragma unroll
    for (int off = 32; off > 0; off >>= 1)
        v += __shfl_down(v, off, 64);

    __shared__ float wave_sums[4];
    const int lane = tidx & 63;
    const int wave = tidx >> 6;
    if (lane == 0) wave_sums[wave] = v;
    __syncthreads();
    if (tidx == 0)
        out[0] = wave_sums[0] + wave_sums[1] + wave_sums[2] + wave_sums[3];
}

extern "C" void kernel_launch(void* const* d_in, const int* in_sizes, int n_in,
                              void* d_out, int out_size, void* d_ws, size_t ws_size,
                              hipStream_t stream) {
    const float* pred   = (const float*)d_in[0];
    const float* target = (const float*)d_in[1];
    float* out = (float*)d_out;
    float* ws  = (float*)d_ws;   // GRID_BLOCKS floats = 8 KB

    wavelet_main<<<GRID_BLOCKS, 256, 0, stream>>>(pred, target, ws);
    wavelet_reduce<<<1, 256, 0, stream>>>(ws, out);
}